// Round 2
// baseline (18048.599 us; speedup 1.0000x reference)
//
#include <hip/hip_runtime.h>
#include <math.h>

// MAGNO decoder, MI355X — round 2: lane=edge relayout, single fused kernel.
//   B=2, NL=2048, NQ=16384, CD=2, CIN=H=64, PH=256, COUT=3, K=32, scales {1,2}.
//
// Layout: block = 256 threads = 4 waves; each wave owns 2 queries; lane = edge
// (lanes 0..31 -> query A's 32 selected edges, lanes 32..63 -> query B's).
// Each lane computes the FULL 64-channel edge MLP for its edge with
// all-static register indexing:
//   h1[64] named regs (layer0 fully unrolled), acc[64] named regs,
//   weights are wave-uniform -> broadcast ds_read_b128 from LDS (no conflicts),
//   so each MAC is exactly one v_fma (no readlane, no per-MAC loads).
// After h3*rn*fac, a 32-lane butterfly gives every lane the decoded 64-vector
// in static regs, so the projection MLP fuses in-wave (each lane owns 8 of the
// 256 hidden channels; w_p0 read from L2).
//
// Exactness: d2 uses __fmul_rn/__fadd_rn (no contraction) so the radius mask
// and top-32 boundary decisions are bit-exact vs the fp32 reference. Selection
// = 32 smallest (d2, pos) lexicographic == jax.lax.top_k stable set.

#define NLAT 2048
#define NQ   16384
#define KNB  32
#define CAP  256     // within-r2 candidates: mean ~78, sigma ~9 -> 256 is ~20 sigma
#define QPB  8       // queries per block (4 waves x 2)

__device__ __forceinline__ float gelu_exact(float x) {
  // jax.nn.gelu(approximate=False): 0.5*x*(1+erf(x/sqrt(2)))
  return 0.5f * x * (1.0f + erff(x * 0.70710678118654752440f));
}

__device__ __forceinline__ void wave_lds_fence() {
  __asm__ volatile("s_waitcnt lgkmcnt(0)" ::: "memory");
}

__launch_bounds__(256, 2)
__global__ void magno_fused(const float* __restrict__ lat,   // [NL,2]
                            const float* __restrict__ rn,    // [B,NL,64]
                            const float* __restrict__ qc,    // [B*NQ,2]
                            const float* __restrict__ w_e0, const float* __restrict__ b_e0,
                            const float* __restrict__ w_e1, const float* __restrict__ b_e1,
                            const float* __restrict__ w_e2, const float* __restrict__ b_e2,
                            const float* __restrict__ w_sw0, const float* __restrict__ b_sw0,
                            const float* __restrict__ w_sw1, const float* __restrict__ b_sw1,
                            const float* __restrict__ w_p0, const float* __restrict__ b_p0,
                            const float* __restrict__ w_p1, const float* __restrict__ b_p1,
                            float* __restrict__ out)         // [B*NQ,3]
{
  const float r1sq = (float)(0.055 * 0.055);
  const float r2sq = (float)((0.055 * 2.0) * (0.055 * 2.0));

  __shared__ float w1s[64 * 64];           // w_e1[i][j]
  __shared__ float w2s[64 * 64];           // w_e2[i][j]
  __shared__ float bias1[64], bias2[64];
  __shared__ float cd2[4][CAP];            // per-wave candidate buffers
  __shared__ int   cidx[4][CAP];
  __shared__ float sd2[QPB][KNB];          // per-query selection
  __shared__ int   sidx[QPB][KNB];
  __shared__ int   snum[QPB];

  // ---- one-time weight staging (only block-wide barrier in the kernel) ----
  for (int t = threadIdx.x; t < 4096; t += 256) {
    w1s[t] = w_e1[t];
    w2s[t] = w_e2[t];
  }
  if (threadIdx.x < 64) {
    bias1[threadIdx.x] = b_e1[threadIdx.x];
    bias2[threadIdx.x] = b_e2[threadIdx.x];
  }
  __syncthreads();

  const int lane = threadIdx.x & 63;
  const int wv   = threadIdx.x >> 6;

  // ---- phase 1: per-wave neighbor search + top-32 selection (2 queries) ---
  for (int sub = 0; sub < 2; ++sub) {
    const int qi = wv * 2 + sub;
    const int gq = blockIdx.x * QPB + qi;
    const float2 qv = *(const float2*)&qc[2 * gq];
    const float q0 = qv.x, q1 = qv.y;

    int nc = 0;
    for (int t = 0; t < NLAT; t += 64) {
      const int l = t + lane;
      const float2 yv = *(const float2*)&lat[2 * l];
      const float dx = q0 - yv.x, dy = q1 - yv.y;
      const float d2 = __fadd_rn(__fmul_rn(dx, dx), __fmul_rn(dy, dy));
      const bool hit = d2 <= r2sq;
      const unsigned long long m = __ballot(hit);
      if (hit) {
        const int pos = nc + __popcll(m & (((unsigned long long)1 << lane) - 1ull));
        if (pos < CAP) { cd2[wv][pos] = d2; cidx[wv][pos] = l; }
      }
      nc += (int)__popcll(m);
    }
    if (nc > CAP) nc = CAP;
    wave_lds_fence();

    if (nc <= KNB) {
      if (lane == 0) snum[qi] = nc;
      if (lane < nc) { sd2[qi][lane] = cd2[wv][lane]; sidx[qi][lane] = cidx[wv][lane]; }
    } else {
      if (lane == 0) snum[qi] = KNB;
      for (int r = 0; r < KNB; ++r) {
        unsigned long long best = ~0ull;
        for (int t = lane; t < nc; t += 64) {
          const unsigned long long key =
              ((unsigned long long)__float_as_uint(cd2[wv][t]) << 32) | (unsigned)t;
          if (key < best) best = key;
        }
#pragma unroll
        for (int off = 32; off > 0; off >>= 1) {
          const unsigned long long o = __shfl_xor(best, off);
          if (o < best) best = o;
        }
        if (lane == 0) {
          const int pos = (int)(best & 0xffffffffu);
          sd2[qi][r]  = __uint_as_float((unsigned)(best >> 32));
          sidx[qi][r] = cidx[wv][pos];
          cd2[wv][pos] = __uint_as_float(0x7f800000u);  // +inf: claimed
        }
        wave_lds_fence();
      }
    }
    wave_lds_fence();
  }

  // ---- phase 2: lane = edge; full edge-MLP per lane, static regs ----------
  const int sub = lane >> 5;
  const int e   = lane & 31;
  const int qi  = wv * 2 + sub;
  const int gq  = blockIdx.x * QPB + qi;
  const int bb  = gq >> 14;                // / NQ
  const float2 qv = *(const float2*)&qc[2 * gq];
  const float q0 = qv.x, q1 = qv.y;

  const int   n_sel  = snum[qi];
  const bool  active = e < n_sel;
  const float d2e = active ? sd2[qi][e] : 1e30f;
  const int   ie  = active ? sidx[qi][e] : 0;
  const float2 yv = *(const float2*)&lat[2 * ie];

  // layer 0 (fully unrolled; weights wave-uniform -> scalar loads)
  float h1[64];
#pragma unroll
  for (int i = 0; i < 64; ++i) {
    const float t = fmaf(yv.x, w_e0[i],
                    fmaf(yv.y, w_e0[64 + i],
                    fmaf(q0,   w_e0[128 + i],
                    fmaf(q1,   w_e0[192 + i], b_e0[i]))));
    h1[i] = gelu_exact(t);
  }

  // layers 1+2 fused: produce h2 in groups of 8, consume into acc immediately
  float acc[64];
#pragma unroll
  for (int j = 0; j < 64; ++j) acc[j] = bias2[j];

  for (int g = 0; g < 8; ++g) {
    float L[8];
#pragma unroll
    for (int k = 0; k < 8; ++k) L[k] = bias1[g * 8 + k];
#pragma unroll
    for (int i = 0; i < 64; ++i) {
      const float4 wA = *(const float4*)&w1s[i * 64 + g * 8];
      const float4 wB = *(const float4*)&w1s[i * 64 + g * 8 + 4];
      const float hi = h1[i];
      L[0] = fmaf(hi, wA.x, L[0]); L[1] = fmaf(hi, wA.y, L[1]);
      L[2] = fmaf(hi, wA.z, L[2]); L[3] = fmaf(hi, wA.w, L[3]);
      L[4] = fmaf(hi, wB.x, L[4]); L[5] = fmaf(hi, wB.y, L[5]);
      L[6] = fmaf(hi, wB.z, L[6]); L[7] = fmaf(hi, wB.w, L[7]);
    }
#pragma unroll
    for (int k = 0; k < 8; ++k) {
      const float hk = gelu_exact(L[k]);
      const float* wr = &w2s[(g * 8 + k) * 64];
#pragma unroll
      for (int jj = 0; jj < 64; jj += 4) {
        const float4 w4 = *(const float4*)&wr[jj];
        acc[jj + 0] = fmaf(hk, w4.x, acc[jj + 0]);
        acc[jj + 1] = fmaf(hk, w4.y, acc[jj + 1]);
        acc[jj + 2] = fmaf(hk, w4.z, acc[jj + 2]);
        acc[jj + 3] = fmaf(hk, w4.w, acc[jj + 3]);
      }
    }
  }

  // ---- phase 3: scale-mix weights, per-lane factor, masked accumulate -----
  float z0 = b_sw1[0], z1 = b_sw1[1];
#pragma unroll
  for (int k = 0; k < 16; ++k) {
    float t = fmaf(q0, w_sw0[k], fmaf(q1, w_sw0[16 + k], b_sw0[k]));
    t = fmaxf(t, 0.f);
    z0 = fmaf(t, w_sw1[2 * k + 0], z0);
    z1 = fmaf(t, w_sw1[2 * k + 1], z1);
  }
  const float mz = fmaxf(z0, z1);
  const float ex0 = expf(z0 - mz), ex1 = expf(z1 - mz);
  const float inv = 1.f / (ex0 + ex1);
  const float sw0 = ex0 * inv, sw1 = ex1 * inv;   // sw0 <-> scale 1.0, sw1 <-> scale 2.0

  const bool v1 = active && (d2e <= r1sq);
  const unsigned long long mB = __ballot(v1);
  const int sh   = lane & 32;
  const int cnt1 = (int)__popcll((mB >> sh) & 0xffffffffull);
  const int cnt2 = n_sel;
  float fac = 0.f;
  if (active) {
    fac = sw1 / (float)(cnt2 > 0 ? cnt2 : 1);
    if (v1) fac += sw0 / (float)(cnt1 > 0 ? cnt1 : 1);
  }

  // contrib = h3 * f_y * fac, then 32-lane butterfly -> every lane holds dec[]
  const float* rnp = rn + ((size_t)bb * NLAT + ie) * 64;
  float dec[64];
#pragma unroll
  for (int jj = 0; jj < 64; jj += 4) {
    const float4 r4 = *(const float4*)&rnp[jj];
    dec[jj + 0] = acc[jj + 0] * r4.x * fac;
    dec[jj + 1] = acc[jj + 1] * r4.y * fac;
    dec[jj + 2] = acc[jj + 2] * r4.z * fac;
    dec[jj + 3] = acc[jj + 3] * r4.w * fac;
  }
#pragma unroll
  for (int jj = 0; jj < 64; ++jj) {
    float v = dec[jj];
    v += __shfl_xor(v, 1);
    v += __shfl_xor(v, 2);
    v += __shfl_xor(v, 4);
    v += __shfl_xor(v, 8);
    v += __shfl_xor(v, 16);
    dec[jj] = v;
  }

  // ---- phase 4: fused projection MLP (lane owns PH channels e*8..e*8+7) ---
  float ph[8];
  {
    const float4 ba = *(const float4*)&b_p0[e * 8];
    const float4 bc = *(const float4*)&b_p0[e * 8 + 4];
    ph[0] = ba.x; ph[1] = ba.y; ph[2] = ba.z; ph[3] = ba.w;
    ph[4] = bc.x; ph[5] = bc.y; ph[6] = bc.z; ph[7] = bc.w;
  }
#pragma unroll
  for (int i = 0; i < 64; ++i) {
    const float di = dec[i];
    const float4 wa = *(const float4*)&w_p0[i * 256 + e * 8];
    const float4 wb = *(const float4*)&w_p0[i * 256 + e * 8 + 4];
    ph[0] = fmaf(di, wa.x, ph[0]); ph[1] = fmaf(di, wa.y, ph[1]);
    ph[2] = fmaf(di, wa.z, ph[2]); ph[3] = fmaf(di, wa.w, ph[3]);
    ph[4] = fmaf(di, wb.x, ph[4]); ph[5] = fmaf(di, wb.y, ph[5]);
    ph[6] = fmaf(di, wb.z, ph[6]); ph[7] = fmaf(di, wb.w, ph[7]);
  }

  float o0 = 0.f, o1 = 0.f, o2 = 0.f;
#pragma unroll
  for (int k = 0; k < 8; ++k) {
    const float gk = gelu_exact(ph[k]);
    const int row = e * 8 + k;
    o0 = fmaf(gk, w_p1[row * 3 + 0], o0);
    o1 = fmaf(gk, w_p1[row * 3 + 1], o1);
    o2 = fmaf(gk, w_p1[row * 3 + 2], o2);
  }
#pragma unroll
  for (int off = 1; off < 32; off <<= 1) {
    o0 += __shfl_xor(o0, off);
    o1 += __shfl_xor(o1, off);
    o2 += __shfl_xor(o2, off);
  }
  if (e == 0) {
    out[(size_t)gq * 3 + 0] = o0 + b_p1[0];
    out[(size_t)gq * 3 + 1] = o1 + b_p1[1];
    out[(size_t)gq * 3 + 2] = o2 + b_p1[2];
  }
}

extern "C" void kernel_launch(void* const* d_in, const int* in_sizes, int n_in,
                              void* d_out, int out_size, void* d_ws, size_t ws_size,
                              hipStream_t stream) {
  const float* lat   = (const float*)d_in[0];
  const float* rn    = (const float*)d_in[1];
  const float* qc    = (const float*)d_in[2];
  const float* w_e0  = (const float*)d_in[3];
  const float* b_e0  = (const float*)d_in[4];
  const float* w_e1  = (const float*)d_in[5];
  const float* b_e1  = (const float*)d_in[6];
  const float* w_e2  = (const float*)d_in[7];
  const float* b_e2  = (const float*)d_in[8];
  const float* w_sw0 = (const float*)d_in[9];
  const float* b_sw0 = (const float*)d_in[10];
  const float* w_sw1 = (const float*)d_in[11];
  const float* b_sw1 = (const float*)d_in[12];
  const float* w_p0  = (const float*)d_in[13];
  const float* b_p0  = (const float*)d_in[14];
  const float* w_p1  = (const float*)d_in[15];
  const float* b_p1  = (const float*)d_in[16];

  float* out = (float*)d_out;

  hipLaunchKernelGGL(magno_fused, dim3((2 * NQ) / QPB), dim3(256), 0, stream,
                     lat, rn, qc, w_e0, b_e0, w_e1, b_e1, w_e2, b_e2,
                     w_sw0, b_sw0, w_sw1, b_sw1, w_p0, b_p0, w_p1, b_p1, out);
}

// Round 3
// 938.600 us; speedup vs baseline: 19.2293x; 19.2293x over previous
//
#include <hip/hip_runtime.h>
#include <math.h>

// MAGNO decoder, MI355X — round 3: lane=edge + SGPR weight streaming + LDS
// register-file. Shapes: B=2, NL=2048, NQ=16384, CD=2, CIN=H=64, PH=256,
// COUT=3, K=32, scales {1,2}.
//
// Round-2 post-mortem: per-lane fp32 arrays (h1/acc/dec/ph ~200 regs) spilled
// to scratch -> 50 GB of memory traffic, VALUBusy 2%. Fixes here:
//  * block = 64 (one wave) owning 2 queries; lane = edge (32 edges/query).
//  * h1 lives in LDS [ch][lane] (lane-major, conflict-free, each lane reads
//    only its own column) -> inner loops stay ROLLED (I$-resident), no
//    dynamic-register indexing, no spill.
//  * Edge-MLP weights are wave-uniform -> read from GLOBAL with uniform
//    indices -> compiler emits s_load; v_fma takes the SGPR operand directly.
//    64 MACs per VALU instruction, zero broadcast cost.
//  * Only acc[64]+L[8] (all statically indexed) live in VGPRs: ~100 VGPRs.
//  * Edge-sum via LDS transpose (stride-65 pad), then fused projection MLP
//    reading the reduced vector from LDS broadcast.
// Exactness: d2 via __fmul_rn/__fadd_rn (no FMA contraction) so radius-mask
// and top-32 boundary decisions are bit-exact vs the fp32 reference.
// Selection = 32 smallest (d2, pos-in-latent-order) == jax.lax.top_k stable.

#define NLAT 2048
#define NQ_TOT 32768   // B * NQ
#define KNB 32
#define CAP 224        // within-r2 candidates: mean ~78, ~16 sigma headroom

__device__ __forceinline__ float gelu_exact(float x) {
  // jax.nn.gelu(approximate=False): 0.5*x*(1+erf(x/sqrt(2)))
  return 0.5f * x * (1.0f + erff(x * 0.70710678118654752440f));
}

__launch_bounds__(64, 2)   // min 2 waves/EU -> VGPR cap 256 (we need ~110)
__global__ void magno_fused(const float* __restrict__ lat,   // [NL,2]
                            const float* __restrict__ rn,    // [B,NL,64]
                            const float* __restrict__ qc,    // [B*NQ,2]
                            const float* __restrict__ w_e0, const float* __restrict__ b_e0,
                            const float* __restrict__ w_e1, const float* __restrict__ b_e1,
                            const float* __restrict__ w_e2, const float* __restrict__ b_e2,
                            const float* __restrict__ w_sw0, const float* __restrict__ b_sw0,
                            const float* __restrict__ w_sw1, const float* __restrict__ b_sw1,
                            const float* __restrict__ w_p0, const float* __restrict__ b_p0,
                            const float* __restrict__ w_p1, const float* __restrict__ b_p1,
                            float* __restrict__ out)         // [B*NQ,3]
{
  const float r1sq = (float)(0.055 * 0.055);
  const float r2sq = (float)((0.055 * 2.0) * (0.055 * 2.0));

  __shared__ float big[64 * 65];      // phase A: h1[ch][lane] (stride 64 use)
                                      // phase B: contrib[edge][ch] (stride 65)
  __shared__ float cd2[CAP];
  __shared__ int   cidx[CAP];
  __shared__ float sd2[2][KNB];
  __shared__ int   sidx[2][KNB];
  __shared__ int   snum[2];
  __shared__ float dec_lds[2][64];

  const int lane = threadIdx.x;

  // ==== phase 1: neighbor search + top-32 selection, per query =============
  for (int s = 0; s < 2; ++s) {
    const int gq = blockIdx.x * 2 + s;
    const float2 qv = *(const float2*)&qc[2 * gq];

    int nc = 0;
    for (int t = 0; t < NLAT; t += 64) {
      const int l = t + lane;
      const float2 yv = *(const float2*)&lat[2 * l];
      const float dx = qv.x - yv.x, dy = qv.y - yv.y;
      const float d2 = __fadd_rn(__fmul_rn(dx, dx), __fmul_rn(dy, dy));
      const bool hit = d2 <= r2sq;
      const unsigned long long m = __ballot(hit);
      if (hit) {
        const int pos = nc + __popcll(m & (((unsigned long long)1 << lane) - 1ull));
        if (pos < CAP) { cd2[pos] = d2; cidx[pos] = l; }
      }
      nc += (int)__popcll(m);
    }
    if (nc > CAP) nc = CAP;   // statistically unreachable
    __syncthreads();

    if (nc <= KNB) {
      if (lane == 0) snum[s] = nc;
      if (lane < nc) { sd2[s][lane] = cd2[lane]; sidx[s][lane] = cidx[lane]; }
      __syncthreads();
    } else {
      if (lane == 0) snum[s] = KNB;
      for (int r = 0; r < KNB; ++r) {
        unsigned long long best = ~0ull;
        for (int t = lane; t < nc; t += 64) {
          const unsigned long long key =
              ((unsigned long long)__float_as_uint(cd2[t]) << 32) | (unsigned)t;
          if (key < best) best = key;
        }
#pragma unroll
        for (int off = 32; off > 0; off >>= 1) {
          const unsigned long long o = __shfl_xor(best, off);
          if (o < best) best = o;
        }
        if (lane == 0) {
          const int pos = (int)(best & 0xffffffffu);
          sd2[s][r]  = __uint_as_float((unsigned)(best >> 32));
          sidx[s][r] = cidx[pos];
          cd2[pos] = __uint_as_float(0x7f800000u);  // +inf: claimed
        }
        __syncthreads();
      }
    }
  }

  // ==== phase 2: lane = edge; edge MLP with SGPR-streamed weights ==========
  const int sub = lane >> 5;          // which of the wave's 2 queries
  const int e   = lane & 31;          // edge slot within query
  const int gq  = blockIdx.x * 2 + sub;
  const int bb  = gq >> 14;           // batch = gq / NQ
  const float2 qv = *(const float2*)&qc[2 * gq];

  const int   n_sel  = snum[sub];
  const bool  active = e < n_sel;
  const float d2e = active ? sd2[sub][e] : 1e30f;
  const int   ie  = active ? sidx[sub][e] : 0;
  const float2 yv = *(const float2*)&lat[2 * ie];

  // layer 0: h1 -> LDS (lane-major; each lane only touches its own column)
#pragma unroll 4
  for (int i = 0; i < 64; ++i) {
    const float t = fmaf(yv.x, w_e0[i],
                    fmaf(yv.y, w_e0[64 + i],
                    fmaf(qv.x, w_e0[128 + i],
                    fmaf(qv.y, w_e0[192 + i], b_e0[i]))));
    big[i * 64 + lane] = gelu_exact(t);
  }
  __syncthreads();

  // layers 1+2 fused: 8 groups of 8 hidden channels; weights via s_load
  float acc[64];
#pragma unroll
  for (int j = 0; j < 64; ++j) acc[j] = b_e2[j];

  for (int g = 0; g < 8; ++g) {
    float L[8];
#pragma unroll
    for (int k = 0; k < 8; ++k) L[k] = b_e1[g * 8 + k];
#pragma unroll 4
    for (int i = 0; i < 64; ++i) {
      const float hi = big[i * 64 + lane];
      const float* wr = &w_e1[i * 64 + g * 8];
      L[0] = fmaf(hi, wr[0], L[0]); L[1] = fmaf(hi, wr[1], L[1]);
      L[2] = fmaf(hi, wr[2], L[2]); L[3] = fmaf(hi, wr[3], L[3]);
      L[4] = fmaf(hi, wr[4], L[4]); L[5] = fmaf(hi, wr[5], L[5]);
      L[6] = fmaf(hi, wr[6], L[6]); L[7] = fmaf(hi, wr[7], L[7]);
    }
    float h2g[8];
#pragma unroll
    for (int k = 0; k < 8; ++k) h2g[k] = gelu_exact(L[k]);
#pragma unroll
    for (int k = 0; k < 8; ++k) {
      const float hk = h2g[k];
      const float* w2r = &w_e2[(g * 8 + k) * 64];
#pragma unroll
      for (int jj = 0; jj < 64; ++jj) acc[jj] = fmaf(hk, w2r[jj], acc[jj]);
    }
  }

  // ==== phase 3: scale-mix softmax + per-edge factor ========================
  float z0 = b_sw1[0], z1 = b_sw1[1];
#pragma unroll
  for (int k = 0; k < 16; ++k) {
    float t = fmaf(qv.x, w_sw0[k], fmaf(qv.y, w_sw0[16 + k], b_sw0[k]));
    t = fmaxf(t, 0.f);
    z0 = fmaf(t, w_sw1[2 * k + 0], z0);
    z1 = fmaf(t, w_sw1[2 * k + 1], z1);
  }
  const float mz = fmaxf(z0, z1);
  const float ex0 = expf(z0 - mz), ex1 = expf(z1 - mz);
  const float inv = 1.f / (ex0 + ex1);
  const float sw0 = ex0 * inv, sw1 = ex1 * inv;  // sw0<->scale1, sw1<->scale2

  const bool v1 = active && (d2e <= r1sq);
  const unsigned long long mB = __ballot(v1);
  const int cnt1 = (int)__popcll((mB >> (lane & 32)) & 0xffffffffull);
  float fac = 0.f;
  if (active) {
    fac = sw1 / (float)n_sel;               // n_sel >= 1 when active
    if (v1) fac += sw0 / (float)cnt1;       // cnt1 >= 1 when v1
  }

  // ==== phase 4: contrib -> LDS (stride-65), transpose-reduce over edges ====
  __syncthreads();                          // h1 reads done; reuse `big`
  const float* rnp = rn + ((size_t)bb * NLAT + ie) * 64;
#pragma unroll 4
  for (int jj = 0; jj < 64; jj += 4) {
    const float4 r4 = *(const float4*)&rnp[jj];
    float* row = &big[lane * 65];
    row[jj + 0] = acc[jj + 0] * r4.x * fac;
    row[jj + 1] = acc[jj + 1] * r4.y * fac;
    row[jj + 2] = acc[jj + 2] * r4.z * fac;
    row[jj + 3] = acc[jj + 3] * r4.w * fac;
  }
  __syncthreads();
  {
    const int qh = lane >> 5;               // query this lane reduces for
    const int j0 = (lane & 31) * 2;         // its 2 channels
    float s0 = 0.f, s1 = 0.f;
#pragma unroll 4
    for (int ee = 0; ee < 32; ++ee) {
      const float* row = &big[(qh * 32 + ee) * 65];
      s0 += row[j0];
      s1 += row[j0 + 1];
    }
    dec_lds[qh][j0]     = s0;
    dec_lds[qh][j0 + 1] = s1;
  }
  __syncthreads();

  // ==== phase 5: fused projection MLP ======================================
  // lane owns PH channels e*8 .. e*8+7 of its query's hidden vector
  float ph[8];
  {
    const float4 ba = *(const float4*)&b_p0[e * 8];
    const float4 bc = *(const float4*)&b_p0[e * 8 + 4];
    ph[0] = ba.x; ph[1] = ba.y; ph[2] = ba.z; ph[3] = ba.w;
    ph[4] = bc.x; ph[5] = bc.y; ph[6] = bc.z; ph[7] = bc.w;
  }
#pragma unroll 4
  for (int i = 0; i < 64; ++i) {
    const float di = dec_lds[sub][i];       // LDS broadcast per half-wave
    const float4 wa = *(const float4*)&w_p0[i * 256 + e * 8];
    const float4 wb = *(const float4*)&w_p0[i * 256 + e * 8 + 4];
    ph[0] = fmaf(di, wa.x, ph[0]); ph[1] = fmaf(di, wa.y, ph[1]);
    ph[2] = fmaf(di, wa.z, ph[2]); ph[3] = fmaf(di, wa.w, ph[3]);
    ph[4] = fmaf(di, wb.x, ph[4]); ph[5] = fmaf(di, wb.y, ph[5]);
    ph[6] = fmaf(di, wb.z, ph[6]); ph[7] = fmaf(di, wb.w, ph[7]);
  }

  float o0 = 0.f, o1 = 0.f, o2 = 0.f;
#pragma unroll
  for (int k = 0; k < 8; ++k) {
    const float gk = gelu_exact(ph[k]);
    const int row = e * 8 + k;
    o0 = fmaf(gk, w_p1[row * 3 + 0], o0);
    o1 = fmaf(gk, w_p1[row * 3 + 1], o1);
    o2 = fmaf(gk, w_p1[row * 3 + 2], o2);
  }
#pragma unroll
  for (int off = 1; off < 32; off <<= 1) {
    o0 += __shfl_xor(o0, off);
    o1 += __shfl_xor(o1, off);
    o2 += __shfl_xor(o2, off);
  }
  if (e == 0) {
    out[(size_t)gq * 3 + 0] = o0 + b_p1[0];
    out[(size_t)gq * 3 + 1] = o1 + b_p1[1];
    out[(size_t)gq * 3 + 2] = o2 + b_p1[2];
  }
}

extern "C" void kernel_launch(void* const* d_in, const int* in_sizes, int n_in,
                              void* d_out, int out_size, void* d_ws, size_t ws_size,
                              hipStream_t stream) {
  const float* lat   = (const float*)d_in[0];
  const float* rn    = (const float*)d_in[1];
  const float* qc    = (const float*)d_in[2];
  const float* w_e0  = (const float*)d_in[3];
  const float* b_e0  = (const float*)d_in[4];
  const float* w_e1  = (const float*)d_in[5];
  const float* b_e1  = (const float*)d_in[6];
  const float* w_e2  = (const float*)d_in[7];
  const float* b_e2  = (const float*)d_in[8];
  const float* w_sw0 = (const float*)d_in[9];
  const float* b_sw0 = (const float*)d_in[10];
  const float* w_sw1 = (const float*)d_in[11];
  const float* b_sw1 = (const float*)d_in[12];
  const float* w_p0  = (const float*)d_in[13];
  const float* b_p0  = (const float*)d_in[14];
  const float* w_p1  = (const float*)d_in[15];
  const float* b_p1  = (const float*)d_in[16];

  float* out = (float*)d_out;

  hipLaunchKernelGGL(magno_fused, dim3(NQ_TOT / 2), dim3(64), 0, stream,
                     lat, rn, qc, w_e0, b_e0, w_e1, b_e1, w_e2, b_e2,
                     w_sw0, b_sw0, w_sw1, b_sw1, w_p0, b_p0, w_p1, b_p1, out);
}